// Round 5
// baseline (365.847 us; speedup 1.0000x reference)
//
#include <hip/hip_runtime.h>
#include <hip/hip_bf16.h>
#include <math.h>

// Cosine attention, n=8, L=S=2048, d=v=64.
// out0 = softmax((q^·k^T)/8) @ V  [8,2048,64]; out1 = softmax scores [8,2048,2048]
// |score| <= 1/8 (unit vectors) -> exp in [0.88,1.13] -> no running max needed.
//
// v5: barrier-free two-phase main kernel.
//   Lesson (r1-r4 counters): per-chunk __syncthreads forces s_waitcnt vmcnt(0)
//   -> every prefetch drained every chunk -> serial L2 round-trips per chunk,
//   plus end-of-kernel store burst. 104 us vs 22 us write roofline.
//   Structure: block = 16 l-rows x 4 waves; wave w privately owns s-quarter
//   [w*512, w*512+512). Phase 1: QK->exp->rowsum only (no LDS/barriers/stores).
//   One barrier -> inv. Phase 2: recompute QK/exp (deterministic), stream
//   normalized score stores inside the loop, PV from REGISTERS via 16x16x16
//   mfma (QK-transposed D-layout == its A-frag layout; HW-validated in r2).
//   One final barrier + LDS reduce of 4 waves' PV partials. 3 barriers total.
//   Keep from r4: XCD pinning (id&7 = batch n -> K[n]+Vt[n] in one 4MB L2;
//   FETCH 20->5 MB measured). Revert from r4: nontemporal stores (WRITE_SIZE
//   137->185 MB measured -- nt defeats write-combining).
// Mask arrives as int32 (harness materializes bool as int) — NOT bytes.

typedef __bf16 bf16x8 __attribute__((ext_vector_type(8)));
typedef __bf16 bf16x4 __attribute__((ext_vector_type(4)));
typedef float f32x4 __attribute__((ext_vector_type(4)));
typedef short short4v __attribute__((ext_vector_type(4)));

#define NB 8
#define LL 2048
#define SS 2048
#define DD 64
#define MWORDS 64      // SS/32 bit-words per row
#define PM_BLOCKS 2048 // mask-pack blocks in fused prep
#define NORM_BLOCKS ((NB * LL * 2) / 4)
#define VT_BLOCKS (NB * (SS / 64))

// PV micro-mma: D[l][v] += E[l][s] * V[s][v]; A comes straight from QK output.
// (operand pairing hardware-validated in round 2: passed with same absmax)
static __device__ __forceinline__ f32x4 pv_mfma16(bf16x4 a, bf16x4 b, f32x4 c) {
#if __has_builtin(__builtin_amdgcn_mfma_f32_16x16x16bf16_1k)
  return __builtin_amdgcn_mfma_f32_16x16x16bf16_1k(
      __builtin_bit_cast(short4v, a), __builtin_bit_cast(short4v, b), c, 0, 0, 0);
#else
  f32x4 d;
  asm("s_nop 1\n\tv_mfma_f32_16x16x16_bf16 %0, %1, %2, %3"
      : "=v"(d)
      : "v"(a), "v"(b), "v"(c));
  return d;
#endif
}

// ---- fused prep: [0,2048) mask bit-pack | [2048,10240) Q/K norm | [10240,10496) V transpose ----
__global__ __launch_bounds__(256) void prep_all(const float* __restrict__ q,
                                                const float* __restrict__ k,
                                                const float* __restrict__ v,
                                                const int* __restrict__ mask,
                                                __bf16* __restrict__ Qb,
                                                __bf16* __restrict__ Kb,
                                                __bf16* __restrict__ Vt,
                                                unsigned* __restrict__ Mb) {
  __shared__ __bf16 tile[64][72];  // used by the Vt branch only
  const int bid = blockIdx.x;
  const int t = threadIdx.x;

  if (bid < PM_BLOCKS) {
    // mask int32 -> 1 bit/element via wave ballot; coalesced 256B/wave/iter.
    // bit j of word w == mask element s = w*32 + j (matches attn consumption).
    const int lane = t & 63;
    const size_t total = (size_t)NB * LL * SS;
    const size_t stride = (size_t)PM_BLOCKS * 256;
    for (size_t i = (size_t)bid * 256 + t; i < total; i += stride) {
      int m = mask[i];
      unsigned long long b = __ballot(m != 0);
      if ((lane & 31) == 0) Mb[i >> 5] = (unsigned)(b >> (lane & 32));
    }
  } else if (bid < PM_BLOCKS + NORM_BLOCKS) {
    // L2-normalize Q (fold 1/8) and K rows, cast to bf16; one wave per row.
    const int nb = bid - PM_BLOCKS;
    const int w = t >> 6, lane = t & 63;
    const int r = nb * 4 + w;
    const float* src;
    __bf16* dst;
    float extra;
    if (r < NB * LL) {
      src = q + (size_t)r * DD;
      dst = Qb + (size_t)r * DD;
      extra = 0.125f;  // fold 1/sqrt(64) into Q
    } else {
      int rk = r - NB * LL;
      src = k + (size_t)rk * DD;
      dst = Kb + (size_t)rk * DD;
      extra = 1.0f;
    }
    float x = src[lane];
    float ss = x * x;
    ss += __shfl_xor(ss, 1);
    ss += __shfl_xor(ss, 2);
    ss += __shfl_xor(ss, 4);
    ss += __shfl_xor(ss, 8);
    ss += __shfl_xor(ss, 16);
    ss += __shfl_xor(ss, 32);
    float nrm = sqrtf(ss);
    float sc = extra / fmaxf(nrm, 1e-12f);
    dst[lane] = (__bf16)(x * sc);
  } else {
    // V [n][s][v] f32 -> Vt [n][v][s] bf16, 64x64 LDS tiles.
    const int vb = bid - PM_BLOCKS - NORM_BLOCKS;  // 0..255
    const int n = vb >> 5;
    const int s0 = (vb & 31) * 64;
#pragma unroll
    for (int it = 0; it < 4; ++it) {
      int idx = t + it * 256;
      int s = idx >> 4, c = idx & 15;
      float4 f = *(const float4*)(v + ((size_t)(n * SS + s0 + s)) * DD + c * 4);
      tile[s][c * 4 + 0] = (__bf16)f.x;
      tile[s][c * 4 + 1] = (__bf16)f.y;
      tile[s][c * 4 + 2] = (__bf16)f.z;
      tile[s][c * 4 + 3] = (__bf16)f.w;
    }
    __syncthreads();
#pragma unroll
    for (int it = 0; it < 4; ++it) {
      int idx = t + it * 256;
      int vv = idx >> 4, c = idx & 15;
      bf16x4 o;
      o[0] = tile[c * 4 + 0][vv];
      o[1] = tile[c * 4 + 1][vv];
      o[2] = tile[c * 4 + 2][vv];
      o[3] = tile[c * 4 + 3][vv];
      *(bf16x4*)(Vt + ((size_t)(n * DD + vv)) * SS + s0 + c * 4) = o;
    }
  }
}

// ---- main: 16 l-rows per block, 4 waves; wave w owns s in [w*512, w*512+512) ----
// Per-lane after transposed QK (step c): l = l0+m16, s = w*512 + c*16 + quad*4 + r.
__global__ __launch_bounds__(256, 4) void attn_main(const __bf16* __restrict__ Qb,
                                                    const __bf16* __restrict__ Kb,
                                                    const __bf16* __restrict__ Vt,
                                                    const unsigned* __restrict__ Mb,
                                                    float* __restrict__ out_val,
                                                    float* __restrict__ out_score) {
  __shared__ float rs[4][16];       // per-wave row sums
  __shared__ float red[4][16][66];  // per-wave PV partials [w][l][v]

  // XCD pinning: id%8 = XCD = batch n -> K[n]+Vt[n] stay in that XCD's L2.
  const int id = blockIdx.x;
  const int n = id & 7;
  const int l0 = (id >> 3) * 16;

  const int t = threadIdx.x;
  const int w = t >> 6;
  const int lane = t & 63;
  const int m16 = lane & 15;
  const int quad = lane >> 4;
  const int sbase = w * 512;

  // Q fragment (B operand of transposed QK): B[n=m16][k=quad*8+j] = Q[l0+m16][k]
  const __bf16* qrow = Qb + ((size_t)(n * LL + l0 + m16)) * DD;
  bf16x8 aq0 = *(const bf16x8*)(qrow + quad * 8);
  bf16x8 aq1 = *(const bf16x8*)(qrow + 32 + quad * 8);

  // K rows for this wave: step c uses rows sbase + c*16 + m16
  const __bf16* krow = Kb + (size_t)n * SS * DD + (size_t)(sbase + m16) * DD;
  // Vt row pointers per v-group: B[k=quad*4+j][n=m16] = V[s][g*16+m16]
  const __bf16* vbase = Vt + (size_t)n * DD * SS + sbase + quad * 4;
  const __bf16* vr0 = vbase + (size_t)(0 * 16 + m16) * SS;
  const __bf16* vr1 = vbase + (size_t)(1 * 16 + m16) * SS;
  const __bf16* vr2 = vbase + (size_t)(2 * 16 + m16) * SS;
  const __bf16* vr3 = vbase + (size_t)(3 * 16 + m16) * SS;

  // all 16 mask words for this lane's (row, s-quarter), held in regs both phases
  const unsigned* mrow_bits = Mb + ((size_t)(n * LL + l0 + m16)) * MWORDS + w * 16;
  unsigned mw[16];
  {
    uint4 a = *(const uint4*)(mrow_bits + 0);
    uint4 b = *(const uint4*)(mrow_bits + 4);
    uint4 cc = *(const uint4*)(mrow_bits + 8);
    uint4 d = *(const uint4*)(mrow_bits + 12);
    mw[0] = a.x;  mw[1] = a.y;  mw[2] = a.z;  mw[3] = a.w;
    mw[4] = b.x;  mw[5] = b.y;  mw[6] = b.z;  mw[7] = b.w;
    mw[8] = cc.x; mw[9] = cc.y; mw[10] = cc.z; mw[11] = cc.w;
    mw[12] = d.x; mw[13] = d.y; mw[14] = d.z; mw[15] = d.w;
  }

  // ---- phase 1: rowsum only (no LDS, no barriers, no stores) ----
  float rsum = 0.f;
  bf16x8 kp0 = *(const bf16x8*)(krow + quad * 8);
  bf16x8 kp1 = *(const bf16x8*)(krow + 32 + quad * 8);
  bf16x8 kq0, kq1;
#pragma unroll
  for (int c = 0; c < 32; ++c) {
    bf16x8 k0 = (c & 1) ? kq0 : kp0;
    bf16x8 k1 = (c & 1) ? kq1 : kp1;
    if (c + 1 < 32) {  // K ping-pong: issue next step's rows now
      const __bf16* kr = krow + (size_t)((c + 1) * 16) * DD;
      if (c & 1) {
        kp0 = *(const bf16x8*)(kr + quad * 8);
        kp1 = *(const bf16x8*)(kr + 32 + quad * 8);
      } else {
        kq0 = *(const bf16x8*)(kr + quad * 8);
        kq1 = *(const bf16x8*)(kr + 32 + quad * 8);
      }
    }
    f32x4 acc = {0.f, 0.f, 0.f, 0.f};
    acc = __builtin_amdgcn_mfma_f32_16x16x32_bf16(k0, aq0, acc, 0, 0, 0);
    acc = __builtin_amdgcn_mfma_f32_16x16x32_bf16(k1, aq1, acc, 0, 0, 0);
    const unsigned b4 = (mw[c >> 1] >> (((c & 1) << 4) + quad * 4)) & 0xFu;
    rsum += ((b4 & 1u) ? __expf(acc[0]) : 0.f) + ((b4 & 2u) ? __expf(acc[1]) : 0.f) +
            ((b4 & 4u) ? __expf(acc[2]) : 0.f) + ((b4 & 8u) ? __expf(acc[3]) : 0.f);
  }
  // reduce quads within wave -> full wave partial for row m16; publish; combine
  rsum += __shfl_xor(rsum, 16);
  rsum += __shfl_xor(rsum, 32);
  if (quad == 0) rs[w][m16] = rsum;
  __syncthreads();
  const float inv_s = 1.0f / (rs[0][m16] + rs[1][m16] + rs[2][m16] + rs[3][m16]);

  // ---- phase 2: recompute e (deterministic), stream score stores, reg-PV ----
  f32x4 acc0 = {0.f, 0.f, 0.f, 0.f};
  f32x4 acc1 = {0.f, 0.f, 0.f, 0.f};
  f32x4 acc2 = {0.f, 0.f, 0.f, 0.f};
  f32x4 acc3 = {0.f, 0.f, 0.f, 0.f};
  float* orow = out_score + ((size_t)(n * LL + l0 + m16)) * SS + sbase + quad * 4;
  kp0 = *(const bf16x8*)(krow + quad * 8);
  kp1 = *(const bf16x8*)(krow + 32 + quad * 8);
#pragma unroll
  for (int c = 0; c < 32; ++c) {
    bf16x8 k0 = (c & 1) ? kq0 : kp0;
    bf16x8 k1 = (c & 1) ? kq1 : kp1;
    if (c + 1 < 32) {
      const __bf16* kr = krow + (size_t)((c + 1) * 16) * DD;
      if (c & 1) {
        kp0 = *(const bf16x8*)(kr + quad * 8);
        kp1 = *(const bf16x8*)(kr + 32 + quad * 8);
      } else {
        kq0 = *(const bf16x8*)(kr + quad * 8);
        kq1 = *(const bf16x8*)(kr + 32 + quad * 8);
      }
    }
    // Vt B-frags (L2-resident; issued early, consumed after QK+exp)
    bf16x4 bv0 = *(const bf16x4*)(vr0 + c * 16);
    bf16x4 bv1 = *(const bf16x4*)(vr1 + c * 16);
    bf16x4 bv2 = *(const bf16x4*)(vr2 + c * 16);
    bf16x4 bv3 = *(const bf16x4*)(vr3 + c * 16);
    f32x4 acc = {0.f, 0.f, 0.f, 0.f};
    acc = __builtin_amdgcn_mfma_f32_16x16x32_bf16(k0, aq0, acc, 0, 0, 0);
    acc = __builtin_amdgcn_mfma_f32_16x16x32_bf16(k1, aq1, acc, 0, 0, 0);
    const unsigned b4 = (mw[c >> 1] >> (((c & 1) << 4) + quad * 4)) & 0xFu;
    const float e0 = (b4 & 1u) ? __expf(acc[0]) : 0.f;
    const float e1 = (b4 & 2u) ? __expf(acc[1]) : 0.f;
    const float e2 = (b4 & 4u) ? __expf(acc[2]) : 0.f;
    const float e3 = (b4 & 8u) ? __expf(acc[3]) : 0.f;
    // streamed, coalesced score store (f32 e * inv; spread over whole kernel)
    f32x4 o = {e0 * inv_s, e1 * inv_s, e2 * inv_s, e3 * inv_s};
    *(f32x4*)(orow + (size_t)c * 16) = o;
    // PV from registers: acc_g[l=quad*4+r][v=g*16+m16] += E * V
    bf16x4 sv;
    sv[0] = (__bf16)e0;
    sv[1] = (__bf16)e1;
    sv[2] = (__bf16)e2;
    sv[3] = (__bf16)e3;
    acc0 = pv_mfma16(sv, bv0, acc0);
    acc1 = pv_mfma16(sv, bv1, acc1);
    acc2 = pv_mfma16(sv, bv2, acc2);
    acc3 = pv_mfma16(sv, bv3, acc3);
  }

  // ---- final reduce: 4 waves' PV partials -> out_value ----
#pragma unroll
  for (int r = 0; r < 4; ++r) {
    red[w][quad * 4 + r][0 * 16 + m16] = acc0[r];
    red[w][quad * 4 + r][1 * 16 + m16] = acc1[r];
    red[w][quad * 4 + r][2 * 16 + m16] = acc2[r];
    red[w][quad * 4 + r][3 * 16 + m16] = acc3[r];
  }
  __syncthreads();
#pragma unroll
  for (int i = 0; i < 4; ++i) {
    const int flat = i * 256 + t;
    const int l = flat >> 6, vv = flat & 63;
    const float s = red[0][l][vv] + red[1][l][vv] + red[2][l][vv] + red[3][l][vv];
    const float tr = rs[0][l] + rs[1][l] + rs[2][l] + rs[3][l];
    out_val[((size_t)(n * LL + l0 + l)) * DD + vv] = s / tr;
  }
}

extern "C" void kernel_launch(void* const* d_in, const int* in_sizes, int n_in,
                              void* d_out, int out_size, void* d_ws, size_t ws_size,
                              hipStream_t stream) {
  const float* q = (const float*)d_in[0];
  const float* k = (const float*)d_in[1];
  const float* v = (const float*)d_in[2];
  const int* mask = (const int*)d_in[3];  // harness materializes bool as int32

  float* out_val = (float*)d_out;                       // [8,2048,64]
  float* out_score = out_val + (size_t)NB * LL * DD;    // [8,2048,2048]

  __bf16* Qb = (__bf16*)d_ws;                  // 2 MB
  __bf16* Kb = Qb + (size_t)NB * LL * DD;      // 2 MB
  __bf16* Vt = Kb + (size_t)NB * SS * DD;      // 2 MB (transposed [n][v][s])
  unsigned* Mb = (unsigned*)(Vt + (size_t)NB * DD * SS);  // 4 MB bitmask

  prep_all<<<dim3(PM_BLOCKS + NORM_BLOCKS + VT_BLOCKS), dim3(256), 0, stream>>>(
      q, k, v, mask, Qb, Kb, Vt, Mb);
  attn_main<<<dim3((LL / 16) * NB), dim3(256), 0, stream>>>(Qb, Kb, Vt, Mb, out_val, out_score);
}

// Round 6
// 307.734 us; speedup vs baseline: 1.1888x; 1.1888x over previous
//
#include <hip/hip_runtime.h>
#include <hip/hip_bf16.h>
#include <math.h>

// Cosine attention, n=8, L=S=2048, d=v=64.
// out0 = softmax((q^·k^T)/8) @ V  [8,2048,64]; out1 = softmax scores [8,2048,2048]
// |score| <= 1/8 (unit vectors) -> exp in [0.88,1.13] -> no running max needed.
//
// v6 = r3 structure (best measured attn: single pass, transposed QK, LDS
// E-exchange PV with 16x16x32 mfma, bf16 stash -> coalesced score epilogue)
// with the barrier drain removed:
//   - per-chunk __syncthreads() (= s_waitcnt vmcnt(0) lgkmcnt(0) + barrier)
//     replaced by s_waitcnt lgkmcnt(0) + raw s_barrier. LDS ordering (the only
//     thing the barrier must guarantee: E ds_writes visible to other waves'
//     ds_reads) needs lgkmcnt ONLY. K/Vt/mask global prefetches now stay in
//     flight ACROSS barriers (counted-vmcnt pattern) instead of being drained
//     16x per kernel. Double-buffer race proof unchanged (1 barrier/chunk).
//   - mask read DIRECTLY as int32 int4/lane, prefetch depth 4 (~1200 cy cover
//     >= 900 cy HBM latency, now that drains are gone). No mask pre-packing:
//     every packing variant cost ~+50 us wall (r3/r4/r5 ledger).
//   - K fragment ping-pong depth 1 (r3 loaded K at chunk top with zero cover).
//   - keep: XCD pinning (FETCH 20->5 MB, r4), stash epilogue + plain stores
//     (WRITE 137 MB proven in r1-r4; r4's nt and r5's 64B-split both -> 185 MB).
// Mask arrives as int32 (harness materializes bool as int) — NOT bytes.

typedef __bf16 bf16x8 __attribute__((ext_vector_type(8)));
typedef __bf16 bf16x4 __attribute__((ext_vector_type(4)));
typedef float f32x4 __attribute__((ext_vector_type(4)));

#define NB 8
#define LL 2048
#define SS 2048
#define DD 64

// ---- prep 1: L2-normalize Q (fold 1/8) and K rows, cast to bf16 ----
// one wave per row; 4 rows per 256-thread block; rows 0..16383 = Q, 16384.. = K
__global__ __launch_bounds__(256) void prep_norm(const float* __restrict__ q,
                                                 const float* __restrict__ k,
                                                 __bf16* __restrict__ Qb,
                                                 __bf16* __restrict__ Kb) {
  int w = threadIdx.x >> 6, lane = threadIdx.x & 63;
  int r = blockIdx.x * 4 + w;
  const float* src;
  __bf16* dst;
  float extra;
  if (r < NB * LL) {
    src = q + (size_t)r * DD;
    dst = Qb + (size_t)r * DD;
    extra = 0.125f;  // fold 1/sqrt(64) into Q
  } else {
    int rk = r - NB * LL;
    src = k + (size_t)rk * DD;
    dst = Kb + (size_t)rk * DD;
    extra = 1.0f;
  }
  float x = src[lane];
  float ss = x * x;
  ss += __shfl_xor(ss, 1);
  ss += __shfl_xor(ss, 2);
  ss += __shfl_xor(ss, 4);
  ss += __shfl_xor(ss, 8);
  ss += __shfl_xor(ss, 16);
  ss += __shfl_xor(ss, 32);
  float nrm = sqrtf(ss);
  float sc = extra / fmaxf(nrm, 1e-12f);
  dst[lane] = (__bf16)(x * sc);
}

// ---- prep 2: V [n][s][v] f32 -> Vt [n][v][s] bf16 (64x64 LDS tiles) ----
__global__ __launch_bounds__(256) void prep_vt(const float* __restrict__ v,
                                               __bf16* __restrict__ Vt) {
  __shared__ __bf16 tile[64][72];
  int n = blockIdx.y;
  int s0 = blockIdx.x * 64;
  int t = threadIdx.x;
#pragma unroll
  for (int it = 0; it < 4; ++it) {
    int idx = t + it * 256;
    int s = idx >> 4, c = idx & 15;
    float4 f = *(const float4*)(v + ((size_t)(n * SS + s0 + s)) * DD + c * 4);
    tile[s][c * 4 + 0] = (__bf16)f.x;
    tile[s][c * 4 + 1] = (__bf16)f.y;
    tile[s][c * 4 + 2] = (__bf16)f.z;
    tile[s][c * 4 + 3] = (__bf16)f.w;
  }
  __syncthreads();
#pragma unroll
  for (int it = 0; it < 4; ++it) {
    int idx = t + it * 256;
    int vv = idx >> 4, c = idx & 15;
    bf16x4 o;
    o[0] = tile[c * 4 + 0][vv];
    o[1] = tile[c * 4 + 1][vv];
    o[2] = tile[c * 4 + 2][vv];
    o[3] = tile[c * 4 + 3][vv];
    *(bf16x4*)(Vt + ((size_t)(n * DD + vv)) * SS + s0 + c * 4) = o;
  }
}

// ---- main: 16 L-rows per block, 8 waves (512 thr), S streamed in 128-col chunks ----
// Wave w: QK for s-cols [w*16, w*16+16) of each chunk (transposed D[s][l]);
// PV split by (v-group = w&3, s-half = (w>>2)*64); end: pairwise acc reduce in LDS.
// Per-lane ownership after transposed QK: (l = l0+m16, s = sc + w*16 + quad*4 + r).
__global__ __launch_bounds__(512, 4) void attn_main(const __bf16* __restrict__ Qb,
                                                    const __bf16* __restrict__ Kb,
                                                    const __bf16* __restrict__ Vt,
                                                    const int* __restrict__ mask,
                                                    float* __restrict__ out_val,
                                                    float* __restrict__ out_score) {
  __shared__ __bf16 e_lds[2][16][136];   // E chunk, row = l (0..15), col = s-in-chunk
  __shared__ float rs_lds[8][16];        // per-wave row-sum partials
  __shared__ float acc_red[4][16][17];   // PV partial exchange (upper s-half waves)

  // XCD pinning: id%8 = XCD = batch n -> K[n]+Vt[n] stay in that XCD's L2.
  const int id = blockIdx.x;
  const int n = id & 7;
  const int l0 = (id >> 3) * 16;

  const int t = threadIdx.x;
  const int w = t >> 6;
  const int lane = t & 63;
  const int m16 = lane & 15;
  const int quad = lane >> 4;
  const int vg = w & 3;            // PV v-group
  const int sh = (w >> 2) * 64;    // PV s-half within chunk

  // Q fragment (B operand of transposed QK): B[n=m16][k=quad*8+j] = Q[l0+m16][k]
  const __bf16* qrow = Qb + ((size_t)(n * LL + l0 + m16)) * DD;
  bf16x8 aq0 = *(const bf16x8*)(qrow + quad * 8);
  bf16x8 aq1 = *(const bf16x8*)(qrow + 32 + quad * 8);

  const __bf16* kbase = Kb + (size_t)n * SS * DD;
  const __bf16* vrow = Vt + ((size_t)(n * DD + vg * 16 + m16)) * SS + sh;
  // per-lane index into mask/out_score: row l = l0+m16, col base = w*16+quad*4
  const size_t mrow = ((size_t)(n * LL + l0 + m16)) * SS + w * 16 + quad * 4;
  const int* mptr = mask + mrow;

  f32x4 acc_o = {0.f, 0.f, 0.f, 0.f};
  float rsum = 0.f;
  bf16x4 stash[16];  // exp'd scores, 4 consecutive s per chunk (static idx -> regs)

  // mask prefetch, depth 4 chunks (int4 per lane per chunk); survives barriers
  int4 mkb[4];
  mkb[0] = *(const int4*)(mptr + 0 * 128);
  mkb[1] = *(const int4*)(mptr + 1 * 128);
  mkb[2] = *(const int4*)(mptr + 2 * 128);
  mkb[3] = *(const int4*)(mptr + 3 * 128);

  // K fragment ping-pong (issue chunk c+1's rows while computing chunk c)
  bf16x8 kpa0, kpa1, kpb0, kpb1;
  {
    const __bf16* kr = kbase + (size_t)(w * 16 + m16) * DD;
    kpa0 = *(const bf16x8*)(kr + quad * 8);
    kpa1 = *(const bf16x8*)(kr + 32 + quad * 8);
  }

#pragma unroll
  for (int c = 0; c < 16; ++c) {
    const int sc = c * 128;
    const bf16x8 kb0 = (c & 1) ? kpb0 : kpa0;
    const bf16x8 kb1 = (c & 1) ? kpb1 : kpa1;
    if (c + 1 < 16) {
      const __bf16* kr = kbase + (size_t)(sc + 128 + w * 16 + m16) * DD;
      if (c & 1) {
        kpa0 = *(const bf16x8*)(kr + quad * 8);
        kpa1 = *(const bf16x8*)(kr + 32 + quad * 8);
      } else {
        kpb0 = *(const bf16x8*)(kr + quad * 8);
        kpb1 = *(const bf16x8*)(kr + 32 + quad * 8);
      }
    }
    // Vt frags for this chunk's PV (consumed after the barrier -> counted wait)
    bf16x8 bv0 = *(const bf16x8*)(vrow + sc + quad * 8);
    bf16x8 bv1 = *(const bf16x8*)(vrow + sc + 32 + quad * 8);
    // mask refill 4 chunks ahead (unrolled -> static index)
    const int4 mk = mkb[c & 3];
    if (c + 4 < 16) mkb[c & 3] = *(const int4*)(mptr + (size_t)(c + 4) * 128);
    // QK transposed: D[row=quad*4+r -> s][col=m16 -> l]
    f32x4 acc = {0.f, 0.f, 0.f, 0.f};
    acc = __builtin_amdgcn_mfma_f32_16x16x32_bf16(kb0, aq0, acc, 0, 0, 0);
    acc = __builtin_amdgcn_mfma_f32_16x16x32_bf16(kb1, aq1, acc, 0, 0, 0);
    float e0 = mk.x ? __expf(acc[0]) : 0.f;
    float e1 = mk.y ? __expf(acc[1]) : 0.f;
    float e2 = mk.z ? __expf(acc[2]) : 0.f;
    float e3 = mk.w ? __expf(acc[3]) : 0.f;
    rsum += (e0 + e1) + (e2 + e3);
    bf16x4 sv;
    sv[0] = (__bf16)e0;
    sv[1] = (__bf16)e1;
    sv[2] = (__bf16)e2;
    sv[3] = (__bf16)e3;
    stash[c] = sv;
    *(bf16x4*)(&e_lds[c & 1][m16][w * 16 + quad * 4]) = sv;
    // LDS-only fence + raw barrier: orders the E ds_writes for cross-wave
    // ds_reads WITHOUT draining global prefetches (no vmcnt(0) here — that
    // drain was the structural stall of r1-r4; __syncthreads emits it).
    asm volatile("s_waitcnt lgkmcnt(0)" ::: "memory");
    __builtin_amdgcn_s_barrier();
    // PV: A = E[l][s-half], B = Vt[v-group][s-half]
    bf16x8 ae0 = *(const bf16x8*)(&e_lds[c & 1][m16][sh + quad * 8]);
    bf16x8 ae1 = *(const bf16x8*)(&e_lds[c & 1][m16][sh + 32 + quad * 8]);
    acc_o = __builtin_amdgcn_mfma_f32_16x16x32_bf16(ae0, bv0, acc_o, 0, 0, 0);
    acc_o = __builtin_amdgcn_mfma_f32_16x16x32_bf16(ae1, bv1, acc_o, 0, 0, 0);
    // dbuf proof: e_lds[c&1] next written at chunk c+2, which is after barrier
    // c+1, which is after all reads of chunk c.
  }

  // rowsum: lane has partial for row l=m16 over its s slices; reduce quads, waves
  rsum += __shfl_xor(rsum, 16);
  rsum += __shfl_xor(rsum, 32);
  if (quad == 0) rs_lds[w][m16] = rsum;
  // upper s-half waves publish PV partials
  if (w >= 4) {
#pragma unroll
    for (int r = 0; r < 4; ++r) acc_red[vg][quad * 4 + r][m16] = acc_o[r];
  }
  __syncthreads();

  float tot = 0.f;
#pragma unroll
  for (int ww = 0; ww < 8; ++ww) tot += rs_lds[ww][m16];
  const float inv_s = 1.0f / tot;  // for score rows (l = l0+m16)

  // out_value: lower s-half waves combine pair partials; C/D rows are l=quad*4+r
  if (w < 4) {
#pragma unroll
    for (int r = 0; r < 4; ++r) {
      const int row = quad * 4 + r;
      float tr = 0.f;
#pragma unroll
      for (int ww = 0; ww < 8; ++ww) tr += rs_lds[ww][row];
      const float o = (acc_o[r] + acc_red[vg][row][m16]) / tr;
      out_val[((size_t)(n * LL + l0 + row)) * DD + vg * 16 + m16] = o;
    }
  }

  // score epilogue: replay stash * inv, coalesced float4 stores (only P write;
  // 8 waves cover 512B per row per step -> full-line merges, WRITE=137MB proven)
  float* orow = out_score + mrow;
#pragma unroll
  for (int c = 0; c < 16; ++c) {
    float4 o;
    o.x = (float)stash[c][0] * inv_s;
    o.y = (float)stash[c][1] * inv_s;
    o.z = (float)stash[c][2] * inv_s;
    o.w = (float)stash[c][3] * inv_s;
    *(float4*)(orow + (size_t)c * 128) = o;
  }
}

extern "C" void kernel_launch(void* const* d_in, const int* in_sizes, int n_in,
                              void* d_out, int out_size, void* d_ws, size_t ws_size,
                              hipStream_t stream) {
  const float* q = (const float*)d_in[0];
  const float* k = (const float*)d_in[1];
  const float* v = (const float*)d_in[2];
  const int* mask = (const int*)d_in[3];  // harness materializes bool as int32

  float* out_val = (float*)d_out;                       // [8,2048,64]
  float* out_score = out_val + (size_t)NB * LL * DD;    // [8,2048,2048]

  __bf16* Qb = (__bf16*)d_ws;                  // 2 MB
  __bf16* Kb = Qb + (size_t)NB * LL * DD;      // 2 MB
  __bf16* Vt = Kb + (size_t)NB * SS * DD;      // 2 MB (transposed [n][v][s])

  prep_norm<<<dim3((NB * LL * 2) / 4), dim3(256), 0, stream>>>(q, k, Qb, Kb);
  prep_vt<<<dim3(SS / 64, NB), dim3(256), 0, stream>>>(v, Vt);
  attn_main<<<dim3((LL / 16) * NB), dim3(512), 0, stream>>>(Qb, Kb, Vt, mask, out_val, out_score);
}

// Round 7
// 294.551 us; speedup vs baseline: 1.2420x; 1.0448x over previous
//
#include <hip/hip_runtime.h>
#include <hip/hip_bf16.h>
#include <math.h>

// Cosine attention, n=8, L=S=2048, d=v=64.
// out0 = softmax((q^·k^T)/8) @ V  [8,2048,64]; out1 = softmax scores [8,2048,2048]
// |score| <= 1/8 (unit vectors) -> exp in [0.88,1.13] -> no running max needed.
//
// v7 = v6 with the vmcnt issue-order bug fixed and pinning reverted.
//   s_waitcnt vmcnt(N) waits for all-but-the-N-NEWEST loads. v6 issued K(c+1)
//   BEFORE the Vt bv loads, so the post-barrier PV (which must wait for bv)
//   was forced to also drain K(c+1) every chunk -> prefetch pulled into the
//   critical path. v7 issues loads in CONSUMPTION order:
//     bv (this chunk, post-barrier) -> mask refill (chunk c+4) -> K (chunk c+1)
//   so PV waits vmcnt(3) and K/mask prefetches genuinely survive the barrier.
//   Grid back to r1-proven dim3(128,8) (unpinned): pinning only helps when the
//   per-XCD streams are tiny (r4 bitmask FETCH=5MB); the 134MB int32 mask +
//   128MB score streams thrash a pinned 4MB L2 (r6 regression component).
//   Keep: lgkmcnt-only barrier (LDS ordering is all the barrier must provide),
//   mask depth 4, stash epilogue + plain stores (WRITE 137MB proven r1-r4).
// Mask arrives as int32 (harness materializes bool as int) — NOT bytes.

typedef __bf16 bf16x8 __attribute__((ext_vector_type(8)));
typedef __bf16 bf16x4 __attribute__((ext_vector_type(4)));
typedef float f32x4 __attribute__((ext_vector_type(4)));

#define NB 8
#define LL 2048
#define SS 2048
#define DD 64

// ---- prep 1: L2-normalize Q (fold 1/8) and K rows, cast to bf16 ----
// one wave per row; 4 rows per 256-thread block; rows 0..16383 = Q, 16384.. = K
__global__ __launch_bounds__(256) void prep_norm(const float* __restrict__ q,
                                                 const float* __restrict__ k,
                                                 __bf16* __restrict__ Qb,
                                                 __bf16* __restrict__ Kb) {
  int w = threadIdx.x >> 6, lane = threadIdx.x & 63;
  int r = blockIdx.x * 4 + w;
  const float* src;
  __bf16* dst;
  float extra;
  if (r < NB * LL) {
    src = q + (size_t)r * DD;
    dst = Qb + (size_t)r * DD;
    extra = 0.125f;  // fold 1/sqrt(64) into Q
  } else {
    int rk = r - NB * LL;
    src = k + (size_t)rk * DD;
    dst = Kb + (size_t)rk * DD;
    extra = 1.0f;
  }
  float x = src[lane];
  float ss = x * x;
  ss += __shfl_xor(ss, 1);
  ss += __shfl_xor(ss, 2);
  ss += __shfl_xor(ss, 4);
  ss += __shfl_xor(ss, 8);
  ss += __shfl_xor(ss, 16);
  ss += __shfl_xor(ss, 32);
  float nrm = sqrtf(ss);
  float sc = extra / fmaxf(nrm, 1e-12f);
  dst[lane] = (__bf16)(x * sc);
}

// ---- prep 2: V [n][s][v] f32 -> Vt [n][v][s] bf16 (64x64 LDS tiles) ----
__global__ __launch_bounds__(256) void prep_vt(const float* __restrict__ v,
                                               __bf16* __restrict__ Vt) {
  __shared__ __bf16 tile[64][72];
  int n = blockIdx.y;
  int s0 = blockIdx.x * 64;
  int t = threadIdx.x;
#pragma unroll
  for (int it = 0; it < 4; ++it) {
    int idx = t + it * 256;
    int s = idx >> 4, c = idx & 15;
    float4 f = *(const float4*)(v + ((size_t)(n * SS + s0 + s)) * DD + c * 4);
    tile[s][c * 4 + 0] = (__bf16)f.x;
    tile[s][c * 4 + 1] = (__bf16)f.y;
    tile[s][c * 4 + 2] = (__bf16)f.z;
    tile[s][c * 4 + 3] = (__bf16)f.w;
  }
  __syncthreads();
#pragma unroll
  for (int it = 0; it < 4; ++it) {
    int idx = t + it * 256;
    int vv = idx >> 4, c = idx & 15;
    bf16x4 o;
    o[0] = tile[c * 4 + 0][vv];
    o[1] = tile[c * 4 + 1][vv];
    o[2] = tile[c * 4 + 2][vv];
    o[3] = tile[c * 4 + 3][vv];
    *(bf16x4*)(Vt + ((size_t)(n * DD + vv)) * SS + s0 + c * 4) = o;
  }
}

// ---- main: 16 L-rows per block, 8 waves (512 thr), S streamed in 128-col chunks ----
// Wave w: QK for s-cols [w*16, w*16+16) of each chunk (transposed D[s][l]);
// PV split by (v-group = w&3, s-half = (w>>2)*64); end: pairwise acc reduce in LDS.
// Per-lane ownership after transposed QK: (l = l0+m16, s = sc + w*16 + quad*4 + r).
__global__ __launch_bounds__(512, 4) void attn_main(const __bf16* __restrict__ Qb,
                                                    const __bf16* __restrict__ Kb,
                                                    const __bf16* __restrict__ Vt,
                                                    const int* __restrict__ mask,
                                                    float* __restrict__ out_val,
                                                    float* __restrict__ out_score) {
  __shared__ __bf16 e_lds[2][16][136];   // E chunk, row = l (0..15), col = s-in-chunk
  __shared__ float rs_lds[8][16];        // per-wave row-sum partials
  __shared__ float acc_red[4][16][17];   // PV partial exchange (upper s-half waves)

  const int n = blockIdx.y;
  const int l0 = blockIdx.x * 16;

  const int t = threadIdx.x;
  const int w = t >> 6;
  const int lane = t & 63;
  const int m16 = lane & 15;
  const int quad = lane >> 4;
  const int vg = w & 3;            // PV v-group
  const int sh = (w >> 2) * 64;    // PV s-half within chunk

  // Q fragment (B operand of transposed QK): B[n=m16][k=quad*8+j] = Q[l0+m16][k]
  const __bf16* qrow = Qb + ((size_t)(n * LL + l0 + m16)) * DD;
  bf16x8 aq0 = *(const bf16x8*)(qrow + quad * 8);
  bf16x8 aq1 = *(const bf16x8*)(qrow + 32 + quad * 8);

  const __bf16* kbase = Kb + (size_t)n * SS * DD;
  const __bf16* vrow = Vt + ((size_t)(n * DD + vg * 16 + m16)) * SS + sh;
  // per-lane index into mask/out_score: row l = l0+m16, col base = w*16+quad*4
  const size_t mrow = ((size_t)(n * LL + l0 + m16)) * SS + w * 16 + quad * 4;
  const int* mptr = mask + mrow;

  f32x4 acc_o = {0.f, 0.f, 0.f, 0.f};
  float rsum = 0.f;
  bf16x4 stash[16];  // exp'd scores, 4 consecutive s per chunk (static idx -> regs)

  // mask prefetch, depth 4 chunks (int4 per lane per chunk); survives barriers
  int4 mkb[4];
  mkb[0] = *(const int4*)(mptr + 0 * 128);
  mkb[1] = *(const int4*)(mptr + 1 * 128);
  mkb[2] = *(const int4*)(mptr + 2 * 128);
  mkb[3] = *(const int4*)(mptr + 3 * 128);

  // K fragment ping-pong (chunk c+1's rows issued at the END of chunk c)
  bf16x8 kpa0, kpa1, kpb0, kpb1;
  {
    const __bf16* kr = kbase + (size_t)(w * 16 + m16) * DD;
    kpa0 = *(const bf16x8*)(kr + quad * 8);
    kpa1 = *(const bf16x8*)(kr + 32 + quad * 8);
  }

#pragma unroll
  for (int c = 0; c < 16; ++c) {
    const int sc = c * 128;
    // ---- loads in CONSUMPTION order (vmcnt waits only drain older loads) ----
    // (1) Vt frags: consumed this chunk, right after the barrier
    bf16x8 bv0 = *(const bf16x8*)(vrow + sc + quad * 8);
    bf16x8 bv1 = *(const bf16x8*)(vrow + sc + 32 + quad * 8);
    // (2) mask refill: consumed at chunk c+4 (unrolled -> static index)
    const int4 mk = mkb[c & 3];
    if (c + 4 < 16) mkb[c & 3] = *(const int4*)(mptr + (size_t)(c + 4) * 128);
    // (3) K for chunk c+1: consumed next chunk -> issued LAST (newest)
    if (c + 1 < 16) {
      const __bf16* kr = kbase + (size_t)(sc + 128 + w * 16 + m16) * DD;
      if (c & 1) {
        kpa0 = *(const bf16x8*)(kr + quad * 8);
        kpa1 = *(const bf16x8*)(kr + 32 + quad * 8);
      } else {
        kpb0 = *(const bf16x8*)(kr + quad * 8);
        kpb1 = *(const bf16x8*)(kr + 32 + quad * 8);
      }
    }
    const bf16x8 kb0 = (c & 1) ? kpb0 : kpa0;
    const bf16x8 kb1 = (c & 1) ? kpb1 : kpa1;
    // QK transposed: D[row=quad*4+r -> s][col=m16 -> l]
    f32x4 acc = {0.f, 0.f, 0.f, 0.f};
    acc = __builtin_amdgcn_mfma_f32_16x16x32_bf16(kb0, aq0, acc, 0, 0, 0);
    acc = __builtin_amdgcn_mfma_f32_16x16x32_bf16(kb1, aq1, acc, 0, 0, 0);
    float e0 = mk.x ? __expf(acc[0]) : 0.f;
    float e1 = mk.y ? __expf(acc[1]) : 0.f;
    float e2 = mk.z ? __expf(acc[2]) : 0.f;
    float e3 = mk.w ? __expf(acc[3]) : 0.f;
    rsum += (e0 + e1) + (e2 + e3);
    bf16x4 sv;
    sv[0] = (__bf16)e0;
    sv[1] = (__bf16)e1;
    sv[2] = (__bf16)e2;
    sv[3] = (__bf16)e3;
    stash[c] = sv;
    *(bf16x4*)(&e_lds[c & 1][m16][w * 16 + quad * 4]) = sv;
    // LDS-only fence + raw barrier: orders the E ds_writes for cross-wave
    // ds_reads WITHOUT draining global prefetches (no vmcnt(0) here).
    asm volatile("s_waitcnt lgkmcnt(0)" ::: "memory");
    __builtin_amdgcn_s_barrier();
    // PV: A = E[l][s-half], B = Vt[v-group][s-half]
    // bv wait = vmcnt(3): mask refill + 2 K loads (newer) keep flying.
    bf16x8 ae0 = *(const bf16x8*)(&e_lds[c & 1][m16][sh + quad * 8]);
    bf16x8 ae1 = *(const bf16x8*)(&e_lds[c & 1][m16][sh + 32 + quad * 8]);
    acc_o = __builtin_amdgcn_mfma_f32_16x16x32_bf16(ae0, bv0, acc_o, 0, 0, 0);
    acc_o = __builtin_amdgcn_mfma_f32_16x16x32_bf16(ae1, bv1, acc_o, 0, 0, 0);
    // dbuf proof: e_lds[c&1] next written at chunk c+2, which is after barrier
    // c+1; barrier c+1's lgkmcnt(0) also drains chunk c's ds_reads. Race-free.
  }

  // rowsum: lane has partial for row l=m16 over its s slices; reduce quads, waves
  rsum += __shfl_xor(rsum, 16);
  rsum += __shfl_xor(rsum, 32);
  if (quad == 0) rs_lds[w][m16] = rsum;
  // upper s-half waves publish PV partials
  if (w >= 4) {
#pragma unroll
    for (int r = 0; r < 4; ++r) acc_red[vg][quad * 4 + r][m16] = acc_o[r];
  }
  __syncthreads();

  float tot = 0.f;
#pragma unroll
  for (int ww = 0; ww < 8; ++ww) tot += rs_lds[ww][m16];
  const float inv_s = 1.0f / tot;  // for score rows (l = l0+m16)

  // out_value: lower s-half waves combine pair partials; C/D rows are l=quad*4+r
  if (w < 4) {
#pragma unroll
    for (int r = 0; r < 4; ++r) {
      const int row = quad * 4 + r;
      float tr = 0.f;
#pragma unroll
      for (int ww = 0; ww < 8; ++ww) tr += rs_lds[ww][row];
      const float o = (acc_o[r] + acc_red[vg][row][m16]) / tr;
      out_val[((size_t)(n * LL + l0 + row)) * DD + vg * 16 + m16] = o;
    }
  }

  // score epilogue: replay stash * inv, coalesced float4 stores (only P write;
  // 8 waves cover 512B per row per step -> full-line merges, WRITE=137MB proven)
  float* orow = out_score + mrow;
#pragma unroll
  for (int c = 0; c < 16; ++c) {
    float4 o;
    o.x = (float)stash[c][0] * inv_s;
    o.y = (float)stash[c][1] * inv_s;
    o.z = (float)stash[c][2] * inv_s;
    o.w = (float)stash[c][3] * inv_s;
    *(float4*)(orow + (size_t)c * 128) = o;
  }
}

extern "C" void kernel_launch(void* const* d_in, const int* in_sizes, int n_in,
                              void* d_out, int out_size, void* d_ws, size_t ws_size,
                              hipStream_t stream) {
  const float* q = (const float*)d_in[0];
  const float* k = (const float*)d_in[1];
  const float* v = (const float*)d_in[2];
  const int* mask = (const int*)d_in[3];  // harness materializes bool as int32

  float* out_val = (float*)d_out;                       // [8,2048,64]
  float* out_score = out_val + (size_t)NB * LL * DD;    // [8,2048,2048]

  __bf16* Qb = (__bf16*)d_ws;                  // 2 MB
  __bf16* Kb = Qb + (size_t)NB * LL * DD;      // 2 MB
  __bf16* Vt = Kb + (size_t)NB * SS * DD;      // 2 MB (transposed [n][v][s])

  prep_norm<<<dim3((NB * LL * 2) / 4), dim3(256), 0, stream>>>(q, k, Qb, Kb);
  prep_vt<<<dim3(SS / 64, NB), dim3(256), 0, stream>>>(v, Vt);
  attn_main<<<dim3(LL / 16, NB), dim3(512), 0, stream>>>(Qb, Kb, Vt, mask, out_val, out_score);
}

// Round 8
// 278.093 us; speedup vs baseline: 1.3156x; 1.0592x over previous
//
#include <hip/hip_runtime.h>
#include <hip/hip_bf16.h>
#include <math.h>

// Cosine attention, n=8, L=S=2048, d=v=64.
// out0 = softmax((q^·k^T)/8) @ V  [8,2048,64]; out1 = softmax scores [8,2048,2048]
// |score| <= 1/8 (unit vectors) -> exp in [0.88,1.13] -> no running max needed.
//
// v8 = r7 skeleton + transaction coalescing of the two big HBM streams.
//   Diagnosis (r7 counters): 225 MB @ 115us = 2.0 TB/s with VALU 8% / MFMA 2.8%
//   -> transaction-rate limited: every global access was a 16-row gather
//   (64 lanes -> 16x 64B segments instead of 4x 256B).
//   Fix 1: mask staged through LDS. Block loads mask[16][128] per chunk with
//     wave-coalesced int4 loads (thread t -> row t>>5, col (t&31)*4; 512B runs),
//     packs to 4 flag-bytes/uint, LDS dbuf; owner lane reads one uint. Depth-2
//     reg pipeline global->reg->LDS->consume rides the existing barrier.
//   Fix 2: score epilogue transposed through LDS. stash -> ep_buf[16][520] bf16
//     in 4 groups of 512 cols; store thread t -> row t>>5, col (t&31)*4+i*128:
//     32 lanes = 512B contiguous per instr. lgkm-only barriers between groups.
//   Keep: transposed QK, LDS E-exchange full-rate 16x16x32 PV, K ping-pong,
//   consumption-order loads, lgkm-only in-loop barrier, unpinned grid,
//   stash epilogue semantics (WRITE=137MB full-line merges proven).
// Mask arrives as int32 (harness materializes bool as int) — NOT bytes.

typedef __bf16 bf16x8 __attribute__((ext_vector_type(8)));
typedef __bf16 bf16x4 __attribute__((ext_vector_type(4)));
typedef float f32x4 __attribute__((ext_vector_type(4)));

#define NB 8
#define LL 2048
#define SS 2048
#define DD 64

// ---- prep 1: L2-normalize Q (fold 1/8) and K rows, cast to bf16 ----
__global__ __launch_bounds__(256) void prep_norm(const float* __restrict__ q,
                                                 const float* __restrict__ k,
                                                 __bf16* __restrict__ Qb,
                                                 __bf16* __restrict__ Kb) {
  int w = threadIdx.x >> 6, lane = threadIdx.x & 63;
  int r = blockIdx.x * 4 + w;
  const float* src;
  __bf16* dst;
  float extra;
  if (r < NB * LL) {
    src = q + (size_t)r * DD;
    dst = Qb + (size_t)r * DD;
    extra = 0.125f;  // fold 1/sqrt(64) into Q
  } else {
    int rk = r - NB * LL;
    src = k + (size_t)rk * DD;
    dst = Kb + (size_t)rk * DD;
    extra = 1.0f;
  }
  float x = src[lane];
  float ss = x * x;
  ss += __shfl_xor(ss, 1);
  ss += __shfl_xor(ss, 2);
  ss += __shfl_xor(ss, 4);
  ss += __shfl_xor(ss, 8);
  ss += __shfl_xor(ss, 16);
  ss += __shfl_xor(ss, 32);
  float nrm = sqrtf(ss);
  float sc = extra / fmaxf(nrm, 1e-12f);
  dst[lane] = (__bf16)(x * sc);
}

// ---- prep 2: V [n][s][v] f32 -> Vt [n][v][s] bf16 (64x64 LDS tiles) ----
__global__ __launch_bounds__(256) void prep_vt(const float* __restrict__ v,
                                               __bf16* __restrict__ Vt) {
  __shared__ __bf16 tile[64][72];
  int n = blockIdx.y;
  int s0 = blockIdx.x * 64;
  int t = threadIdx.x;
#pragma unroll
  for (int it = 0; it < 4; ++it) {
    int idx = t + it * 256;
    int s = idx >> 4, c = idx & 15;
    float4 f = *(const float4*)(v + ((size_t)(n * SS + s0 + s)) * DD + c * 4);
    tile[s][c * 4 + 0] = (__bf16)f.x;
    tile[s][c * 4 + 1] = (__bf16)f.y;
    tile[s][c * 4 + 2] = (__bf16)f.z;
    tile[s][c * 4 + 3] = (__bf16)f.w;
  }
  __syncthreads();
#pragma unroll
  for (int it = 0; it < 4; ++it) {
    int idx = t + it * 256;
    int vv = idx >> 4, c = idx & 15;
    bf16x4 o;
    o[0] = tile[c * 4 + 0][vv];
    o[1] = tile[c * 4 + 1][vv];
    o[2] = tile[c * 4 + 2][vv];
    o[3] = tile[c * 4 + 3][vv];
    *(bf16x4*)(Vt + ((size_t)(n * DD + vv)) * SS + s0 + c * 4) = o;
  }
}

// ---- main: 16 L-rows per block, 8 waves (512 thr), S streamed in 128-col chunks ----
__global__ __launch_bounds__(512, 4) void attn_main(const __bf16* __restrict__ Qb,
                                                    const __bf16* __restrict__ Kb,
                                                    const __bf16* __restrict__ Vt,
                                                    const int* __restrict__ mask,
                                                    float* __restrict__ out_val,
                                                    float* __restrict__ out_score) {
  __shared__ __bf16 e_lds[2][16][136];     // E chunk, row = l, col = s-in-chunk
  __shared__ unsigned mb_lds[2][16][33];   // packed mask (4 flag-bytes per uint)
  __shared__ float rs_lds[8][16];          // per-wave row-sum partials
  __shared__ float acc_red[4][16][17];     // PV partial exchange
  __shared__ float inv_row[16];            // 1/rowsum for epilogue threads
  __shared__ __bf16 ep_buf[16][520];       // epilogue transpose buffer (512+8 pad)

  const int n = blockIdx.y;
  const int l0 = blockIdx.x * 16;

  const int t = threadIdx.x;
  const int w = t >> 6;
  const int lane = t & 63;
  const int m16 = lane & 15;
  const int quad = lane >> 4;
  const int vg = w & 3;            // PV v-group
  const int sh = (w >> 2) * 64;    // PV s-half within chunk

  // Q fragment (B operand of transposed QK): B[n=m16][k=quad*8+j] = Q[l0+m16][k]
  const __bf16* qrow = Qb + ((size_t)(n * LL + l0 + m16)) * DD;
  bf16x8 aq0 = *(const bf16x8*)(qrow + quad * 8);
  bf16x8 aq1 = *(const bf16x8*)(qrow + 32 + quad * 8);

  const __bf16* kbase = Kb + (size_t)n * SS * DD;
  const __bf16* vrow = Vt + ((size_t)(n * DD + vg * 16 + m16)) * SS + sh;

  // coalesced mask staging coords: thread t -> row t>>5, cols (t&31)*4..+4
  const int mrow_st = t >> 5;
  const int mcol_st = (t & 31) * 4;
  const int* mgbase = mask + ((size_t)(n * LL + l0 + mrow_st)) * SS + mcol_st;

  f32x4 acc_o = {0.f, 0.f, 0.f, 0.f};
  float rsum = 0.f;
  bf16x4 stash[16];  // exp'd scores, 4 consecutive s per chunk (static idx -> regs)

  // mask reg pipeline, depth 2: global -> reg (1 chunk) -> LDS (1 chunk) -> use
  int4 mreg[2];
  mreg[0] = *(const int4*)(mgbase + 0 * 128);    // m(0)
  mreg[1] = *(const int4*)(mgbase + 1 * 128);    // m(1)

  // K fragment ping-pong
  bf16x8 kpa0, kpa1, kpb0, kpb1;
  {
    const __bf16* kr = kbase + (size_t)(w * 16 + m16) * DD;
    kpa0 = *(const bf16x8*)(kr + quad * 8);
    kpa1 = *(const bf16x8*)(kr + 32 + quad * 8);
  }

  // prologue: stage m(0) into LDS buf 0
  {
    const int4 m = mreg[0];
    mb_lds[0][mrow_st][t & 31] = (unsigned)((m.x != 0) | ((m.y != 0) << 8) |
                                            ((m.z != 0) << 16) | ((m.w != 0) << 24));
  }
  asm volatile("s_waitcnt lgkmcnt(0)" ::: "memory");
  __builtin_amdgcn_s_barrier();

#pragma unroll
  for (int c = 0; c < 16; ++c) {
    const int sc = c * 128;
    // ---- global loads in consumption order ----
    // (1) Vt frags: consumed this chunk, right after the barrier
    bf16x8 bv0 = *(const bf16x8*)(vrow + sc + quad * 8);
    bf16x8 bv1 = *(const bf16x8*)(vrow + sc + 32 + quad * 8);
    // (2) K for chunk c+1: consumed next chunk (QK)
    if (c + 1 < 16) {
      const __bf16* kr = kbase + (size_t)(sc + 128 + w * 16 + m16) * DD;
      if (c & 1) {
        kpa0 = *(const bf16x8*)(kr + quad * 8);
        kpa1 = *(const bf16x8*)(kr + 32 + quad * 8);
      } else {
        kpb0 = *(const bf16x8*)(kr + quad * 8);
        kpb1 = *(const bf16x8*)(kr + 32 + quad * 8);
      }
    }
    // (3) mask(c+2) global -> reg (coalesced 512B runs; consumed next chunk)
    if (c + 2 < 16) mreg[c & 1] = *(const int4*)(mgbase + (size_t)(c + 2) * 128);
    // (4) stage m(c+1) reg -> LDS (loaded during chunk c-1; in flight 1 chunk)
    if (c + 1 < 16) {
      const int4 m = mreg[(c + 1) & 1];
      mb_lds[(c + 1) & 1][mrow_st][t & 31] =
          (unsigned)((m.x != 0) | ((m.y != 0) << 8) | ((m.z != 0) << 16) |
                     ((m.w != 0) << 24));
    }
    // (5) this chunk's mask flags for owner lane: one uint = 4 flag bytes
    const unsigned mu = mb_lds[c & 1][m16][w * 4 + quad];
    // QK transposed: D[row=quad*4+r -> s][col=m16 -> l]
    const bf16x8 kb0 = (c & 1) ? kpb0 : kpa0;
    const bf16x8 kb1 = (c & 1) ? kpb1 : kpa1;
    f32x4 acc = {0.f, 0.f, 0.f, 0.f};
    acc = __builtin_amdgcn_mfma_f32_16x16x32_bf16(kb0, aq0, acc, 0, 0, 0);
    acc = __builtin_amdgcn_mfma_f32_16x16x32_bf16(kb1, aq1, acc, 0, 0, 0);
    float e0 = (mu & 0x1u) ? __expf(acc[0]) : 0.f;
    float e1 = (mu & 0x100u) ? __expf(acc[1]) : 0.f;
    float e2 = (mu & 0x10000u) ? __expf(acc[2]) : 0.f;
    float e3 = (mu & 0x1000000u) ? __expf(acc[3]) : 0.f;
    rsum += (e0 + e1) + (e2 + e3);
    bf16x4 sv;
    sv[0] = (__bf16)e0;
    sv[1] = (__bf16)e1;
    sv[2] = (__bf16)e2;
    sv[3] = (__bf16)e3;
    stash[c] = sv;
    *(bf16x4*)(&e_lds[c & 1][m16][w * 16 + quad * 4]) = sv;
    // LDS-only fence + raw barrier (orders e_lds AND mb_lds writes; global
    // prefetches stay in flight — no vmcnt(0)).
    asm volatile("s_waitcnt lgkmcnt(0)" ::: "memory");
    __builtin_amdgcn_s_barrier();
    // PV: A = E[l][s-half], B = Vt[v-group][s-half]
    bf16x8 ae0 = *(const bf16x8*)(&e_lds[c & 1][m16][sh + quad * 8]);
    bf16x8 ae1 = *(const bf16x8*)(&e_lds[c & 1][m16][sh + 32 + quad * 8]);
    acc_o = __builtin_amdgcn_mfma_f32_16x16x32_bf16(ae0, bv0, acc_o, 0, 0, 0);
    acc_o = __builtin_amdgcn_mfma_f32_16x16x32_bf16(ae1, bv1, acc_o, 0, 0, 0);
    // dbuf proofs: e_lds[c&1]/mb_lds[(c+1)&1] rewritten only after the barrier
    // that follows their last reads (std double-buffer argument).
  }

  // rowsum: reduce quads within wave, publish, combine across waves
  rsum += __shfl_xor(rsum, 16);
  rsum += __shfl_xor(rsum, 32);
  if (quad == 0) rs_lds[w][m16] = rsum;
  if (w >= 4) {
#pragma unroll
    for (int r = 0; r < 4; ++r) acc_red[vg][quad * 4 + r][m16] = acc_o[r];
  }
  __syncthreads();

  float tot = 0.f;
#pragma unroll
  for (int ww = 0; ww < 8; ++ww) tot += rs_lds[ww][m16];
  const float inv_s = 1.0f / tot;  // row l = l0+m16
  if (t < 16) inv_row[t] = inv_s;  // t<16 -> w=0, m16=t

  // out_value: lower s-half waves combine pair partials
  if (w < 4) {
#pragma unroll
    for (int r = 0; r < 4; ++r) {
      const int row = quad * 4 + r;
      float tr = 0.f;
#pragma unroll
      for (int ww = 0; ww < 8; ++ww) tr += rs_lds[ww][row];
      const float o = (acc_o[r] + acc_red[vg][row][m16]) / tr;
      out_val[((size_t)(n * LL + l0 + row)) * DD + vg * 16 + m16] = o;
    }
  }
  __syncthreads();  // inv_row visible; rs/acc_red reads done

  // ---- score epilogue: LDS transpose -> fully coalesced stores ----
  // 4 groups of 512 s-cols; store thread t -> row t>>5, col (t&31)*4 + i*128:
  // 32 consecutive lanes write 512B contiguous per instruction.
  const int erow = t >> 5;
  const int ecol = (t & 31) * 4;
  const float einv = inv_row[erow];
  float* obase = out_score + ((size_t)(n * LL + l0 + erow)) * SS;
#pragma unroll
  for (int g = 0; g < 4; ++g) {
#pragma unroll
    for (int i = 0; i < 4; ++i) {
      *(bf16x4*)(&ep_buf[m16][i * 128 + w * 16 + quad * 4]) = stash[g * 4 + i];
    }
    asm volatile("s_waitcnt lgkmcnt(0)" ::: "memory");
    __builtin_amdgcn_s_barrier();
#pragma unroll
    for (int i = 0; i < 4; ++i) {
      const bf16x4 ev = *(const bf16x4*)(&ep_buf[erow][ecol + i * 128]);
      float4 o;
      o.x = (float)ev[0] * einv;
      o.y = (float)ev[1] * einv;
      o.z = (float)ev[2] * einv;
      o.w = (float)ev[3] * einv;
      *(float4*)(obase + g * 512 + ecol + i * 128) = o;
    }
    asm volatile("s_waitcnt lgkmcnt(0)" ::: "memory");
    __builtin_amdgcn_s_barrier();  // reads done before next group's writes
  }
}

extern "C" void kernel_launch(void* const* d_in, const int* in_sizes, int n_in,
                              void* d_out, int out_size, void* d_ws, size_t ws_size,
                              hipStream_t stream) {
  const float* q = (const float*)d_in[0];
  const float* k = (const float*)d_in[1];
  const float* v = (const float*)d_in[2];
  const int* mask = (const int*)d_in[3];  // harness materializes bool as int32

  float* out_val = (float*)d_out;                       // [8,2048,64]
  float* out_score = out_val + (size_t)NB * LL * DD;    // [8,2048,2048]

  __bf16* Qb = (__bf16*)d_ws;                  // 2 MB
  __bf16* Kb = Qb + (size_t)NB * LL * DD;      // 2 MB
  __bf16* Vt = Kb + (size_t)NB * SS * DD;      // 2 MB (transposed [n][v][s])

  prep_norm<<<dim3((NB * LL * 2) / 4), dim3(256), 0, stream>>>(q, k, Qb, Kb);
  prep_vt<<<dim3(SS / 64, NB), dim3(256), 0, stream>>>(v, Vt);
  attn_main<<<dim3(LL / 16, NB), dim3(512), 0, stream>>>(Qb, Kb, Vt, mask, out_val, out_score);
}